// Round 14
// baseline (593.836 us; speedup 1.0000x reference)
//
#include <hip/hip_runtime.h>
#include <math.h>

#define NN    16384
#define NE    262144
#define NHEAD 4
#define HC    512
#define NG    8

typedef __bf16 bf16x8 __attribute__((ext_vector_type(8)));
typedef float floatx4 __attribute__((ext_vector_type(4)));
typedef float f32x2 __attribute__((ext_vector_type(2)));

__device__ __forceinline__ f32x2 sp2(float s) { return (f32x2){s, s}; }
__device__ __forceinline__ f32x2 pkmax(f32x2 a, f32x2 b) {
    f32x2 r; r.x = fmaxf(a.x, b.x); r.y = fmaxf(a.y, b.y); return r;
}

__device__ __forceinline__ unsigned short f2bf(float f) {
    union { float f; unsigned u; } v{f};
    unsigned r = v.u + 0x7FFFu + ((v.u >> 16) & 1u);  // RNE
    return (unsigned short)(r >> 16);
}
__device__ __forceinline__ float bf2f(unsigned short b) {
    return __uint_as_float((unsigned)b << 16);
}

// unpack uint4 (8 packed bf16) -> 4 x f32x2 (channel pairs)
__device__ __forceinline__ void unpk8v(uint4 v, f32x2* f) {
    f[0] = (f32x2){__uint_as_float(v.x << 16), __uint_as_float(v.x & 0xFFFF0000u)};
    f[1] = (f32x2){__uint_as_float(v.y << 16), __uint_as_float(v.y & 0xFFFF0000u)};
    f[2] = (f32x2){__uint_as_float(v.z << 16), __uint_as_float(v.z & 0xFFFF0000u)};
    f[3] = (f32x2){__uint_as_float(v.w << 16), __uint_as_float(v.w & 0xFFFF0000u)};
}

// async global->LDS, 16B per lane (dest must be linear: wave_base + lane*16)
#define GLD16(g, l) __builtin_amdgcn_global_load_lds( \
    (const __attribute__((address_space(1))) void*)(g), \
    (__attribute__((address_space(3))) void*)(l), 16, 0, 0)

// lightweight grid barrier for grids <= 256 blocks (1 block/CU => co-resident)
__device__ __forceinline__ void gbar(int* cnt, int nblk) {
    __syncthreads();
    if (threadIdx.x == 0) {
        __threadfence();                 // make this block's stores/atomics visible
        atomicAdd(cnt, 1);               // device-scope arrive
        while (__hip_atomic_load(cnt, __ATOMIC_ACQUIRE, __HIP_MEMORY_SCOPE_AGENT) < nblk)
            __builtin_amdgcn_s_sleep(8);
        __threadfence();                 // reader-side fence (invalidate stale lines)
    }
    __syncthreads();
}

// ---------- CSR build ----------
__global__ __launch_bounds__(1024) void k_scan(const int* __restrict__ cnt,
                                               int* __restrict__ rp,
                                               int* __restrict__ offp,
                                               const int* __restrict__ batch,
                                               int* __restrict__ gcnt) {
    __shared__ int part[1024];
    int t = threadIdx.x;
    if (t < NG) {  // fused gcnt: batch sorted -> binary searches
        int lb[2];
#pragma unroll
        for (int q = 0; q < 2; q++) {
            int target = t + q;
            int lo = 0, hi = NN;
            while (lo < hi) {
                int mid = (lo + hi) >> 1;
                if (batch[mid] < target) lo = mid + 1; else hi = mid;
            }
            lb[q] = lo;
        }
        gcnt[t] = lb[1] - lb[0];
    }
    int base = t * 16;
    int loc[16];
    int s = 0;
#pragma unroll
    for (int i = 0; i < 16; i++) { loc[i] = s; s += cnt[base + i]; }
    part[t] = s;
    __syncthreads();
    for (int off = 1; off < 1024; off <<= 1) {
        int v = 0;
        if (t >= off) v = part[t - off];
        __syncthreads();
        if (t >= off) part[t] += v;
        __syncthreads();
    }
    int excl = (t == 0) ? 0 : part[t - 1];
#pragma unroll
    for (int i = 0; i < 16; i++) {
        int r = excl + loc[i];
        rp[base + i] = r;
        offp[base + i] = r;
    }
    if (t == 1023) rp[NN] = excl + s;
}

__global__ void k_fill(const int* __restrict__ dst, const int* __restrict__ src,
                       const float* __restrict__ ea, int* __restrict__ offp,
                       int* __restrict__ csrc, float2* __restrict__ ce) {
    int e = blockIdx.x * 256 + threadIdx.x;
    if (e < NE) {
        int d = dst[e];
        int pos = atomicAdd(&offp[d], 1);
        csrc[pos] = src[e];
        ce[pos] = *(const float2*)(ea + 2 * (size_t)e);
    }
}

// ---------- merged preamble: hist (1024 blocks) + wt4 (256) + lin1 (4096) ----------
__global__ __launch_bounds__(256) void k_pre(
        const int* __restrict__ dst, int* __restrict__ cnt,
        const float* __restrict__ W0, const float* __restrict__ W1,
        const float* __restrict__ W2, const float* __restrict__ W3,
        unsigned short* __restrict__ Wt2, unsigned short* __restrict__ Wt3,
        const float* __restrict__ x, const float* __restrict__ Wl,
        const float* __restrict__ Wr,
        unsigned short* __restrict__ xl, unsigned short* __restrict__ xr) {
    __shared__ float tile[64][65];
    int bid = blockIdx.x;
    int t = threadIdx.x;
    if (bid >= 1280) {
        // ---- lin1: layer-1 linear (K=5), bf16 out ----
        int n = (bid - 1280) * 4 + (t >> 6);
        int lane = t & 63;
        int j0 = lane << 3;
        float xs[5];
#pragma unroll
        for (int k = 0; k < 5; k++) xs[k] = x[n * 5 + k];
        float al[8] = {}, ar[8] = {};
#pragma unroll
        for (int k = 0; k < 5; k++) {
            float4 wl0 = *(const float4*)(Wl + k * 512 + j0);
            float4 wl1 = *(const float4*)(Wl + k * 512 + j0 + 4);
            float4 wr0 = *(const float4*)(Wr + k * 512 + j0);
            float4 wr1 = *(const float4*)(Wr + k * 512 + j0 + 4);
            al[0] += xs[k] * wl0.x; al[1] += xs[k] * wl0.y; al[2] += xs[k] * wl0.z; al[3] += xs[k] * wl0.w;
            al[4] += xs[k] * wl1.x; al[5] += xs[k] * wl1.y; al[6] += xs[k] * wl1.z; al[7] += xs[k] * wl1.w;
            ar[0] += xs[k] * wr0.x; ar[1] += xs[k] * wr0.y; ar[2] += xs[k] * wr0.z; ar[3] += xs[k] * wr0.w;
            ar[4] += xs[k] * wr1.x; ar[5] += xs[k] * wr1.y; ar[6] += xs[k] * wr1.z; ar[7] += xs[k] * wr1.w;
        }
        ushort4 o0, o1;
        o0.x = f2bf(al[0]); o0.y = f2bf(al[1]); o0.z = f2bf(al[2]); o0.w = f2bf(al[3]);
        o1.x = f2bf(al[4]); o1.y = f2bf(al[5]); o1.z = f2bf(al[6]); o1.w = f2bf(al[7]);
        *(ushort4*)(xl + (size_t)n * 512 + j0) = o0;
        *(ushort4*)(xl + (size_t)n * 512 + j0 + 4) = o1;
        o0.x = f2bf(ar[0]); o0.y = f2bf(ar[1]); o0.z = f2bf(ar[2]); o0.w = f2bf(ar[3]);
        o1.x = f2bf(ar[4]); o1.y = f2bf(ar[5]); o1.z = f2bf(ar[6]); o1.w = f2bf(ar[7]);
        *(ushort4*)(xr + (size_t)n * 512 + j0) = o0;
        *(ushort4*)(xr + (size_t)n * 512 + j0 + 4) = o1;
    } else if (bid >= 1024) {
        // ---- wt4: 4 weight transposes (f32 -> bf16) ----
        int wb = bid - 1024;
        int mat = wb >> 6, sub = wb & 63;
        const float* W = (mat == 0) ? W0 : (mat == 1) ? W1 : (mat == 2) ? W2 : W3;
        unsigned short* Wt = (mat == 0) ? Wt2 : (mat == 1) ? (Wt2 + 512 * 512)
                           : (mat == 2) ? Wt3 : (Wt3 + 512 * 512);
        int n0 = (sub & 7) * 64, k0 = (sub >> 3) * 64;
        int lr = t >> 4;
        int lc = (t & 15) << 2;
        for (int r = lr; r < 64; r += 16) {
            float4 v = *(const float4*)(W + (size_t)(k0 + r) * 512 + n0 + lc);
            tile[r][lc] = v.x; tile[r][lc + 1] = v.y; tile[r][lc + 2] = v.z; tile[r][lc + 3] = v.w;
        }
        __syncthreads();
        for (int r = lr; r < 64; r += 16) {
            ushort4 o;
            o.x = f2bf(tile[lc + 0][r]); o.y = f2bf(tile[lc + 1][r]);
            o.z = f2bf(tile[lc + 2][r]); o.w = f2bf(tile[lc + 3][r]);
            *(ushort4*)(Wt + (size_t)(n0 + r) * 512 + k0 + lc) = o;
        }
    } else {
        // ---- hist ----
        int e = bid * 256 + t;
        atomicAdd(&cnt[dst[e]], 1);
    }
}

// ---------- bf16 MFMA GEMM (global_load_lds width-16, linear LDS, XCD-swizzled grid) ----------
#define BM 128
#define BN 128
#define BK 64

__global__ __launch_bounds__(256) void k_gemm_bf16(
        const unsigned short* __restrict__ Ab,
        const unsigned short* __restrict__ Bt,
        unsigned short* __restrict__ xl, unsigned short* __restrict__ xr) {
    __shared__ unsigned short As[BM * BK];
    __shared__ unsigned short Bs[BN * BK];
    int t = threadIdx.x;
    int bid = blockIdx.x;
    int xcd = bid & 7, r = bid >> 3;
    int m0 = (xcd * 16 + (r & 15)) * BM;
    int n0 = (r >> 4) * BN;
    int wid = t >> 6, lane = t & 63;
    int wm = (wid >> 1) * 64, wn = (wid & 1) * 64;
    int lrow = lane & 15, quad = lane >> 4;
    floatx4 acc[4][4] = {};
    for (int k0 = 0; k0 < 512; k0 += BK) {
        __syncthreads();
#pragma unroll
        for (int it = 0; it < 4; it++) {
            int cid = it * 256 + t;
            int row = cid >> 3, ch = cid & 7;
            // LDS dest byte = cid*16 = wave_base + lane*16 (linear, matches HW)
            GLD16(Ab + (size_t)(m0 + row) * 512 + k0 + ch * 8, As + cid * 8);
            GLD16(Bt + (size_t)(n0 + row) * 512 + k0 + ch * 8, Bs + cid * 8);
        }
        __syncthreads();
#pragma unroll
        for (int ko = 0; ko < 2; ko++) {
            bf16x8 af[4], bfr[4];
#pragma unroll
            for (int i = 0; i < 4; i++) {
                af[i]  = *(const bf16x8*)&As[(wm + i * 16 + lrow) * BK + ko * 32 + quad * 8];
                bfr[i] = *(const bf16x8*)&Bs[(wn + i * 16 + lrow) * BK + ko * 32 + quad * 8];
            }
#pragma unroll
            for (int i = 0; i < 4; i++)
#pragma unroll
                for (int j = 0; j < 4; j++)
                    acc[i][j] = __builtin_amdgcn_mfma_f32_16x16x32_bf16(af[i], bfr[j], acc[i][j], 0, 0, 0);
        }
    }
#pragma unroll
    for (int i = 0; i < 4; i++) {
        int row = m0 + wm + i * 16 + quad * 4;
#pragma unroll
        for (int j = 0; j < 4; j++) {
            int col = n0 + wn + j * 16 + lrow;
            unsigned short* dstp = (col < 512) ? (xl + (size_t)row * 512 + col)
                                               : (xr + (size_t)row * 512 + (col - 512));
#pragma unroll
            for (int rr = 0; rr < 4; rr++) dstp[(size_t)rr * 512] = f2bf(acc[i][j][rr]);
        }
    }
}

// ---------- fused GATv2 edge phase: 1 wave/block (fine-grain scheduling),
// ---------- 4-wide edge pipeline, SGPR CSR walk, packed math ----------
__global__ __launch_bounds__(64) void k_attn(
        const unsigned short* __restrict__ xl, const unsigned short* __restrict__ xr,
        const int* __restrict__ rp, const int* __restrict__ csrc,
        const float2* __restrict__ ce, const float* __restrict__ We,
        const float* __restrict__ att, const float* __restrict__ bias,
        unsigned short* __restrict__ out) {
    // one node per 64-thread block: CU slot frees per-node, no straggler coupling
    int n = __builtin_amdgcn_readfirstlane(blockIdx.x);
    int lane = threadIdx.x;
    int c0 = lane << 3;
    f32x2 wv0[4], wv1[4], av[4], rv[4];
    {
        float4 a = *(const float4*)(We + c0), b = *(const float4*)(We + c0 + 4);
        wv0[0] = (f32x2){a.x, a.y}; wv0[1] = (f32x2){a.z, a.w};
        wv0[2] = (f32x2){b.x, b.y}; wv0[3] = (f32x2){b.z, b.w};
        a = *(const float4*)(We + 512 + c0); b = *(const float4*)(We + 512 + c0 + 4);
        wv1[0] = (f32x2){a.x, a.y}; wv1[1] = (f32x2){a.z, a.w};
        wv1[2] = (f32x2){b.x, b.y}; wv1[3] = (f32x2){b.z, b.w};
        a = *(const float4*)(att + c0); b = *(const float4*)(att + c0 + 4);
        av[0] = (f32x2){a.x, a.y}; av[1] = (f32x2){a.z, a.w};
        av[2] = (f32x2){b.x, b.y}; av[3] = (f32x2){b.z, b.w};
        uint4 vr = *(const uint4*)(xr + (size_t)n * 512 + c0);
        unpk8v(vr, rv);
    }
    float l = 0.f;
    f32x2 acc[4] = {sp2(0.f), sp2(0.f), sp2(0.f), sp2(0.f)};
    int beg = rp[n], end = rp[n + 1];
    uint4 cv[4];
    float2 cev[4];
    if (beg < end) {
#pragma unroll
        for (int k = 0; k < 4; k++) {
            int q = beg + k; q = (q < end) ? q : end - 1;
            cv[k] = *(const uint4*)(xl + (size_t)csrc[q] * 512 + c0);
            cev[k] = ce[q];
        }
    }
    int i = beg;
    for (; i + 3 < end; i += 4) {
        uint4 a[4]; float2 d[4];
#pragma unroll
        for (int k = 0; k < 4; k++) { a[k] = cv[k]; d[k] = cev[k]; }
#pragma unroll
        for (int k = 0; k < 4; k++) {
            int q = i + 4 + k; q = (q < end) ? q : end - 1;
            cv[k] = *(const uint4*)(xl + (size_t)csrc[q] * 512 + c0);
            cev[k] = ce[q];
        }
        f32x2 lv[4][4];
#pragma unroll
        for (int k = 0; k < 4; k++) unpk8v(a[k], lv[k]);
        float p[4];
#pragma unroll
        for (int k = 0; k < 4; k++) {
            f32x2 dx = sp2(d[k].x), dy = sp2(d[k].y);
            f32x2 pv = sp2(0.f);
#pragma unroll
            for (int j = 0; j < 4; j++) {
                f32x2 v = lv[k][j] + rv[j] + dx * wv0[j] + dy * wv1[j];
                v = pkmax(v, sp2(0.2f) * v);   // leaky_relu(0.2)
                pv += av[j] * v;
            }
            p[k] = pv.x + pv.y;
        }
        // 4 independent 16-lane reduce chains, interleaved
#pragma unroll
        for (int m = 1; m <= 8; m <<= 1) {
#pragma unroll
            for (int k = 0; k < 4; k++) p[k] += __shfl_xor(p[k], m);
        }
        float w[4];
#pragma unroll
        for (int k = 0; k < 4; k++) { w[k] = __expf(fminf(p[k], 60.f)); l += w[k]; }
#pragma unroll
        for (int j = 0; j < 4; j++) {
            f32x2 t0 = sp2(w[0]) * lv[0][j] + sp2(w[1]) * lv[1][j];
            f32x2 t1 = sp2(w[2]) * lv[2][j] + sp2(w[3]) * lv[3][j];
            acc[j] += t0 + t1;
        }
    }
    // tail: cv[k] holds edge min(i+k, end-1) = edge i+k for k < rem
    int rem = end - i;
#pragma unroll
    for (int k = 0; k < 3; k++) {
        if (k < rem) {
            f32x2 lv[4];
            unpk8v(cv[k], lv);
            f32x2 dx = sp2(cev[k].x), dy = sp2(cev[k].y);
            f32x2 pv = sp2(0.f);
#pragma unroll
            for (int j = 0; j < 4; j++) {
                f32x2 v = lv[j] + rv[j] + dx * wv0[j] + dy * wv1[j];
                v = pkmax(v, sp2(0.2f) * v);
                pv += av[j] * v;
            }
            float p = pv.x + pv.y;
            p += __shfl_xor(p, 1);
            p += __shfl_xor(p, 2);
            p += __shfl_xor(p, 4);
            p += __shfl_xor(p, 8);
            float w = __expf(fminf(p, 60.f));
            l += w;
            f32x2 wv = sp2(w);
#pragma unroll
            for (int j = 0; j < 4; j++) acc[j] += wv * lv[j];
        }
    }
    float inv = 1.f / (l + 1e-16f);
    const float* bb = bias + c0;
    float4 b0 = *(const float4*)bb, b1 = *(const float4*)(bb + 4);
    ushort4 o0, o1;
    o0.x = f2bf(acc[0].x * inv + b0.x); o0.y = f2bf(acc[0].y * inv + b0.y);
    o0.z = f2bf(acc[1].x * inv + b0.z); o0.w = f2bf(acc[1].y * inv + b0.w);
    o1.x = f2bf(acc[2].x * inv + b1.x); o1.y = f2bf(acc[2].y * inv + b1.y);
    o1.z = f2bf(acc[3].x * inv + b1.z); o1.w = f2bf(acc[3].y * inv + b1.w);
    *(ushort4*)(out + (size_t)n * 512 + c0) = o0;
    *(ushort4*)(out + (size_t)n * 512 + c0 + 4) = o1;
}

// ---------- fused BN: stats -> manual 256-block barrier -> apply ----------
__global__ __launch_bounds__(256) void k_bn(
        const unsigned short* __restrict__ v,
        const unsigned short* __restrict__ resid,
        double* __restrict__ sum, double* __restrict__ sumsq,
        const float* __restrict__ g, const float* __restrict__ beta,
        unsigned short* __restrict__ outb, int* __restrict__ bar) {
    __shared__ float ls[4][512];
    __shared__ float lq[4][512];
    int t = threadIdx.x;
    int bid = blockIdx.x;
    // ---- phase 1: stats (identical math to old k_bnstat: 256 blocks x 64 rows) ----
    {
        int w = t >> 6, lane = t & 63;
        int c0 = lane << 3;
        int r0 = bid * 64 + w * 16;
        f32x2 sv[4] = {sp2(0.f), sp2(0.f), sp2(0.f), sp2(0.f)};
        f32x2 qv[4] = {sp2(0.f), sp2(0.f), sp2(0.f), sp2(0.f)};
#pragma unroll 4
        for (int r = r0; r < r0 + 16; r++) {
            uint4 u = *(const uint4*)(v + (size_t)r * 512 + c0);
            f32x2 vv[4];
            unpk8v(u, vv);
#pragma unroll
            for (int j = 0; j < 4; j++) { sv[j] += vv[j]; qv[j] += vv[j] * vv[j]; }
        }
#pragma unroll
        for (int j = 0; j < 4; j++) {
            ls[w][c0 + 2 * j] = sv[j].x; ls[w][c0 + 2 * j + 1] = sv[j].y;
            lq[w][c0 + 2 * j] = qv[j].x; lq[w][c0 + 2 * j + 1] = qv[j].y;
        }
        __syncthreads();
        int c2 = t << 1;
#pragma unroll
        for (int k = 0; k < 2; k++) {
            int c = c2 + k;
            float s4 = ls[0][c] + ls[1][c] + ls[2][c] + ls[3][c];
            float q4 = lq[0][c] + lq[1][c] + lq[2][c] + lq[3][c];
            atomicAdd(sum + c, (double)s4);
            atomicAdd(sumsq + c, (double)q4);
        }
    }
    gbar(bar, 256);
    // ---- phase 2: apply (each block does 32 chunks of 1024 elems = old 8192-blk grid) ----
    int c = (t << 2) & 511;
    double2 s01 = *(const double2*)(sum + c);
    double2 s23 = *(const double2*)(sum + c + 2);
    double2 q01 = *(const double2*)(sumsq + c);
    double2 q23 = *(const double2*)(sumsq + c + 2);
    float4 gg = *(const float4*)(g + c);
    float4 be = *(const float4*)(beta + c);
    const double invN = 1.0 / NN;
    double mu0 = s01.x * invN, mu1 = s01.y * invN, mu2 = s23.x * invN, mu3 = s23.y * invN;
    float sc0 = gg.x * rsqrtf((float)(q01.x * invN - mu0 * mu0) + 1e-5f);
    float sc1 = gg.y * rsqrtf((float)(q01.y * invN - mu1 * mu1) + 1e-5f);
    float sc2 = gg.z * rsqrtf((float)(q23.x * invN - mu2 * mu2) + 1e-5f);
    float sc3 = gg.w * rsqrtf((float)(q23.y * invN - mu3 * mu3) + 1e-5f);
    float fm0 = (float)mu0, fm1 = (float)mu1, fm2 = (float)mu2, fm3 = (float)mu3;
#pragma unroll 4
    for (int q = 0; q < 32; q++) {
        int i = (((bid << 5) | q) * 256 + t) << 2;
        ushort4 vu = *(const ushort4*)(v + i);
        float y0 = (bf2f(vu.x) - fm0) * sc0 + be.x;
        float y1 = (bf2f(vu.y) - fm1) * sc1 + be.y;
        float y2 = (bf2f(vu.z) - fm2) * sc2 + be.z;
        float y3 = (bf2f(vu.w) - fm3) * sc3 + be.w;
        y0 = y0 > 0.f ? y0 : expm1f(y0);
        y1 = y1 > 0.f ? y1 : expm1f(y1);
        y2 = y2 > 0.f ? y2 : expm1f(y2);
        y3 = y3 > 0.f ? y3 : expm1f(y3);
        if (resid) {
            ushort4 ru = *(const ushort4*)(resid + i);
            y0 += bf2f(ru.x); y1 += bf2f(ru.y); y2 += bf2f(ru.z); y3 += bf2f(ru.w);
        }
        ushort4 o;
        o.x = f2bf(y0); o.y = f2bf(y1); o.z = f2bf(y2); o.w = f2bf(y3);
        *(ushort4*)(outb + i) = o;
    }
}

// ---------- fused tail: pool -> bar -> h1 -> bar -> emb -> bar -> fin (256 blocks) ----------
__global__ __launch_bounds__(256) void k_tail(
        const unsigned short* __restrict__ xb, const int* __restrict__ batch,
        float* __restrict__ pooled, const int* __restrict__ gcnt,
        const float* __restrict__ W1, const float* __restrict__ b1,
        const float* __restrict__ W2, const float* __restrict__ b2,
        const float* __restrict__ clsW, const float* __restrict__ clsb,
        float* __restrict__ h1acc, float* __restrict__ embacc,
        float* __restrict__ outp, int* __restrict__ bars) {
    __shared__ float lacc[NG][512];   // 16KB; reused by later phases
    int t = threadIdx.x;
    int bid = blockIdx.x;
    // ---- phase 1: mean-pool accumulate (256 blocks x 64 rows; identical to k_pool) ----
    for (int i = t; i < NG * 512; i += 256) ((float*)lacc)[i] = 0.f;
    __syncthreads();
    {
        int r0 = bid * 64;
        int c2 = t << 1;
        for (int r = r0; r < r0 + 64; r++) {
            int g = batch[r];
            unsigned u = *(const unsigned*)(xb + (size_t)r * 512 + c2);
            lacc[g][c2]     += __uint_as_float(u << 16);
            lacc[g][c2 + 1] += __uint_as_float(u & 0xFFFF0000u);
        }
        __syncthreads();
        int gmin = batch[r0], gmax = batch[r0 + 63];
        for (int g = gmin; g <= gmax; g++)
            for (int i = t; i < 512; i += 256)
                atomicAdd(&pooled[g * 512 + i], lacc[g][i]);
    }
    gbar(&bars[0], 256);
    // ---- phase 2: h1 partial dots (blocks 0..127: 8 g x 16 c-slices of 32) ----
    if (bid < 128) {
        int g = bid >> 4, s = bid & 15;
        int c0 = s * 32;
        float acc = 0.f;
#pragma unroll
        for (int c = 0; c < 32; c++)
            acc += pooled[g * 512 + c0 + c] * W1[(size_t)(c0 + c) * 256 + t];
        atomicAdd(&h1acc[g * 256 + t], acc);
    }
    gbar(&bars[1], 256);
    // ---- phase 3: emb partials (blocks 0..63: 8 g x 8 c-slices of 32) ----
    if (bid < 64) {
        int g = bid >> 3, s = bid & 7;
        int c0 = s * 32;
        float* hs = &lacc[0][0];
        if (t < 32) {
            float inv = 1.f / (float)gcnt[g];
            hs[t] = fmaxf(h1acc[g * 256 + c0 + t] * inv + b1[c0 + t], 0.f);
        }
        __syncthreads();
        float acc = 0.f;
#pragma unroll
        for (int c = 0; c < 32; c++)
            acc += hs[c] * W2[(size_t)(c0 + c) * 256 + t];
        atomicAdd(&embacc[g * 256 + t], acc);
    }
    gbar(&bars[2], 256);
    // ---- phase 4: emb + b2 -> out, logits (blocks 0..7) ----
    if (bid < 8) {
        int g = bid;
        float* es = &lacc[1][0];
        float e = embacc[g * 256 + t] + b2[t];
        outp[NG * 12 + g * 256 + t] = e;  // emb
        es[t] = e;
        __syncthreads();
        if (t < 12) {
            float lg = clsb[t];
            for (int c = 0; c < 256; c++) lg += es[c] * clsW[c * 12 + t];
            outp[g * 12 + t] = lg;  // logits
        }
    }
}

extern "C" void kernel_launch(void* const* d_in, const int* in_sizes, int n_in,
                              void* d_out, int out_size, void* d_ws, size_t ws_size,
                              hipStream_t stream) {
    const float* x     = (const float*)d_in[0];
    const float* ea    = (const float*)d_in[1];
    const int*   ei    = (const int*)d_in[2];
    const int*   batch = (const int*)d_in[3];
    const int* src = ei;
    const int* dst = ei + NE;

    float* base = (float*)d_ws;
    size_t off = 0;
    auto alloc = [&](size_t n) -> float* {   // n = FLOAT count (256-aligned)
        float* p = base + off;
        off += (n + 255) & ~(size_t)255;
        return p;
    };
    unsigned short* xl  = (unsigned short*)alloc((size_t)NN * 256);  // [NN,512] bf16
    unsigned short* xr  = (unsigned short*)alloc((size_t)NN * 256);
    unsigned short* Yb  = (unsigned short*)alloc((size_t)NN * 256);  // attn out bf16
    unsigned short* XbA = (unsigned short*)alloc((size_t)NN * 256);  // layer-out ping
    unsigned short* XbB = (unsigned short*)alloc((size_t)NN * 256);  // layer-out pong
    unsigned short* Wt2 = (unsigned short*)alloc(512 * 1024 / 2);
    unsigned short* Wt3 = (unsigned short*)alloc(512 * 1024 / 2);
    int*      rp    = (int*)alloc(NN + 1);
    int*      offp  = (int*)alloc(NN);
    int*      csrc  = (int*)alloc(NE);
    float2*   ce    = (float2*)alloc((size_t)NE * 2);
    // --- zero-init region: cnt | bsum3 | pooled | h1acc | embacc | bars (one memset) ---
    int*      cnt   = (int*)alloc(NN);           // 16384 floats
    double*   bsum3 = (double*)alloc(3 * 2048);  // 6144 floats
    float*    pooled= alloc(NG * 512);           // 4096 floats
    float*    h1acc = alloc(NG * 256);           // 2048 floats
    float*    embacc= alloc(NG * 256);           // 2048 floats
    int*      bars  = (int*)alloc(256);          // 256 floats (barrier counters)
    // --- end zero-init region (30976 floats total) ---
    int*      gcnt  = (int*)alloc(NG);
    float*    outp  = (float*)d_out;  // [0,96): logits, [96,2144): emb

    hipMemsetAsync(cnt, 0, 30976 * sizeof(float), stream);  // cnt+bsum3+pooled+h1acc+embacc+bars
    // merged preamble: hist (blocks 0..1023) + wt4 (1024..1279) + lin1 (1280..5375)
    k_pre<<<5376, 256, 0, stream>>>(dst, cnt,
                                    (const float*)d_in[11], (const float*)d_in[12],
                                    (const float*)d_in[18], (const float*)d_in[19],
                                    Wt2, Wt3,
                                    x, (const float*)d_in[4], (const float*)d_in[5],
                                    xl, xr);
    k_scan<<<1, 1024, 0, stream>>>(cnt, rp, offp, batch, gcnt);
    k_fill<<<NE / 256, 256, 0, stream>>>(dst, src, ea, offp, csrc, ce);

    unsigned short* X = XbA;   // current layer output
    unsigned short* Xp = XbB;  // previous layer output (residual)
    for (int l = 0; l < 3; l++) {
        const float* We  = (const float*)d_in[4 + l * 7 + 2];
        const float* att = (const float*)d_in[4 + l * 7 + 3];
        const float* cb  = (const float*)d_in[4 + l * 7 + 4];
        const float* bg  = (const float*)d_in[4 + l * 7 + 5];
        const float* bb  = (const float*)d_in[4 + l * 7 + 6];

        if (l > 0) {
            k_gemm_bf16<<<1024, 256, 0, stream>>>(Xp, (l == 1) ? Wt2 : Wt3, xl, xr);
        }
        // one node per 64-thread block: finest scheduling granularity
        k_attn<<<NN, 64, 0, stream>>>(xl, xr, rp, csrc, ce, We, att, cb, Yb);

        double* bsum = bsum3 + l * 1024;
        double* bsq  = bsum + 512;
        // fused BN stats+apply with manual 256-block barrier
        k_bn<<<256, 256, 0, stream>>>(Yb, (l == 0) ? nullptr : Xp, bsum, bsq,
                                      bg, bb, X, bars + l);

        unsigned short* tmp = Xp; Xp = X; X = tmp;  // Xp now holds this layer's output
    }

    const float* geW1 = (const float*)d_in[25];
    const float* geb1 = (const float*)d_in[26];
    const float* geW2 = (const float*)d_in[27];
    const float* geb2 = (const float*)d_in[28];
    const float* clsW = (const float*)d_in[29];
    const float* clsb = (const float*)d_in[30];

    // fused tail: pool + 3-stage head with manual barriers (256 blocks)
    k_tail<<<256, 256, 0, stream>>>((const unsigned short*)Xp, batch, pooled, gcnt,
                                    geW1, geb1, geW2, geb2, clsW, clsb,
                                    h1acc, embacc, outp, bars + 4);
}

// Round 15
// 461.770 us; speedup vs baseline: 1.2860x; 1.2860x over previous
//
#include <hip/hip_runtime.h>
#include <math.h>

#define NN    16384
#define NE    262144
#define NHEAD 4
#define HC    512
#define NG    8

typedef __bf16 bf16x8 __attribute__((ext_vector_type(8)));
typedef float floatx4 __attribute__((ext_vector_type(4)));
typedef float f32x2 __attribute__((ext_vector_type(2)));

__device__ __forceinline__ f32x2 sp2(float s) { return (f32x2){s, s}; }
__device__ __forceinline__ f32x2 pkmax(f32x2 a, f32x2 b) {
    f32x2 r; r.x = fmaxf(a.x, b.x); r.y = fmaxf(a.y, b.y); return r;
}

__device__ __forceinline__ unsigned short f2bf(float f) {
    union { float f; unsigned u; } v{f};
    unsigned r = v.u + 0x7FFFu + ((v.u >> 16) & 1u);  // RNE
    return (unsigned short)(r >> 16);
}
__device__ __forceinline__ float bf2f(unsigned short b) {
    return __uint_as_float((unsigned)b << 16);
}

// unpack uint4 (8 packed bf16) -> 4 x f32x2 (channel pairs)
__device__ __forceinline__ void unpk8v(uint4 v, f32x2* f) {
    f[0] = (f32x2){__uint_as_float(v.x << 16), __uint_as_float(v.x & 0xFFFF0000u)};
    f[1] = (f32x2){__uint_as_float(v.y << 16), __uint_as_float(v.y & 0xFFFF0000u)};
    f[2] = (f32x2){__uint_as_float(v.z << 16), __uint_as_float(v.z & 0xFFFF0000u)};
    f[3] = (f32x2){__uint_as_float(v.w << 16), __uint_as_float(v.w & 0xFFFF0000u)};
}

// async global->LDS, 16B per lane (dest must be linear: wave_base + lane*16)
#define GLD16(g, l) __builtin_amdgcn_global_load_lds( \
    (const __attribute__((address_space(1))) void*)(g), \
    (__attribute__((address_space(3))) void*)(l), 16, 0, 0)

// ---------- CSR build ----------
__global__ __launch_bounds__(1024) void k_scan(const int* __restrict__ cnt,
                                               int* __restrict__ rp,
                                               int* __restrict__ offp,
                                               const int* __restrict__ batch,
                                               int* __restrict__ gcnt) {
    __shared__ int part[1024];
    int t = threadIdx.x;
    if (t < NG) {  // fused gcnt: batch sorted -> binary searches
        int lb[2];
#pragma unroll
        for (int q = 0; q < 2; q++) {
            int target = t + q;
            int lo = 0, hi = NN;
            while (lo < hi) {
                int mid = (lo + hi) >> 1;
                if (batch[mid] < target) lo = mid + 1; else hi = mid;
            }
            lb[q] = lo;
        }
        gcnt[t] = lb[1] - lb[0];
    }
    int base = t * 16;
    int loc[16];
    int s = 0;
#pragma unroll
    for (int i = 0; i < 16; i++) { loc[i] = s; s += cnt[base + i]; }
    part[t] = s;
    __syncthreads();
    for (int off = 1; off < 1024; off <<= 1) {
        int v = 0;
        if (t >= off) v = part[t - off];
        __syncthreads();
        if (t >= off) part[t] += v;
        __syncthreads();
    }
    int excl = (t == 0) ? 0 : part[t - 1];
#pragma unroll
    for (int i = 0; i < 16; i++) {
        int r = excl + loc[i];
        rp[base + i] = r;
        offp[base + i] = r;
    }
    if (t == 1023) rp[NN] = excl + s;
}

__global__ void k_fill(const int* __restrict__ dst, const int* __restrict__ src,
                       const float* __restrict__ ea, int* __restrict__ offp,
                       int* __restrict__ csrc, float2* __restrict__ ce) {
    int e = blockIdx.x * 256 + threadIdx.x;
    if (e < NE) {
        int d = dst[e];
        int pos = atomicAdd(&offp[d], 1);
        csrc[pos] = src[e];
        ce[pos] = *(const float2*)(ea + 2 * (size_t)e);
    }
}

// ---------- merged preamble: hist (1024 blocks) + wt4 (256) + lin1 (4096) ----------
__global__ __launch_bounds__(256) void k_pre(
        const int* __restrict__ dst, int* __restrict__ cnt,
        const float* __restrict__ W0, const float* __restrict__ W1,
        const float* __restrict__ W2, const float* __restrict__ W3,
        unsigned short* __restrict__ Wt2, unsigned short* __restrict__ Wt3,
        const float* __restrict__ x, const float* __restrict__ Wl,
        const float* __restrict__ Wr,
        unsigned short* __restrict__ xl, unsigned short* __restrict__ xr) {
    __shared__ float tile[64][65];
    int bid = blockIdx.x;
    int t = threadIdx.x;
    if (bid >= 1280) {
        // ---- lin1: layer-1 linear (K=5), bf16 out ----
        int n = (bid - 1280) * 4 + (t >> 6);
        int lane = t & 63;
        int j0 = lane << 3;
        float xs[5];
#pragma unroll
        for (int k = 0; k < 5; k++) xs[k] = x[n * 5 + k];
        float al[8] = {}, ar[8] = {};
#pragma unroll
        for (int k = 0; k < 5; k++) {
            float4 wl0 = *(const float4*)(Wl + k * 512 + j0);
            float4 wl1 = *(const float4*)(Wl + k * 512 + j0 + 4);
            float4 wr0 = *(const float4*)(Wr + k * 512 + j0);
            float4 wr1 = *(const float4*)(Wr + k * 512 + j0 + 4);
            al[0] += xs[k] * wl0.x; al[1] += xs[k] * wl0.y; al[2] += xs[k] * wl0.z; al[3] += xs[k] * wl0.w;
            al[4] += xs[k] * wl1.x; al[5] += xs[k] * wl1.y; al[6] += xs[k] * wl1.z; al[7] += xs[k] * wl1.w;
            ar[0] += xs[k] * wr0.x; ar[1] += xs[k] * wr0.y; ar[2] += xs[k] * wr0.z; ar[3] += xs[k] * wr0.w;
            ar[4] += xs[k] * wr1.x; ar[5] += xs[k] * wr1.y; ar[6] += xs[k] * wr1.z; ar[7] += xs[k] * wr1.w;
        }
        ushort4 o0, o1;
        o0.x = f2bf(al[0]); o0.y = f2bf(al[1]); o0.z = f2bf(al[2]); o0.w = f2bf(al[3]);
        o1.x = f2bf(al[4]); o1.y = f2bf(al[5]); o1.z = f2bf(al[6]); o1.w = f2bf(al[7]);
        *(ushort4*)(xl + (size_t)n * 512 + j0) = o0;
        *(ushort4*)(xl + (size_t)n * 512 + j0 + 4) = o1;
        o0.x = f2bf(ar[0]); o0.y = f2bf(ar[1]); o0.z = f2bf(ar[2]); o0.w = f2bf(ar[3]);
        o1.x = f2bf(ar[4]); o1.y = f2bf(ar[5]); o1.z = f2bf(ar[6]); o1.w = f2bf(ar[7]);
        *(ushort4*)(xr + (size_t)n * 512 + j0) = o0;
        *(ushort4*)(xr + (size_t)n * 512 + j0 + 4) = o1;
    } else if (bid >= 1024) {
        // ---- wt4: 4 weight transposes (f32 -> bf16) ----
        int wb = bid - 1024;
        int mat = wb >> 6, sub = wb & 63;
        const float* W = (mat == 0) ? W0 : (mat == 1) ? W1 : (mat == 2) ? W2 : W3;
        unsigned short* Wt = (mat == 0) ? Wt2 : (mat == 1) ? (Wt2 + 512 * 512)
                           : (mat == 2) ? Wt3 : (Wt3 + 512 * 512);
        int n0 = (sub & 7) * 64, k0 = (sub >> 3) * 64;
        int lr = t >> 4;
        int lc = (t & 15) << 2;
        for (int r = lr; r < 64; r += 16) {
            float4 v = *(const float4*)(W + (size_t)(k0 + r) * 512 + n0 + lc);
            tile[r][lc] = v.x; tile[r][lc + 1] = v.y; tile[r][lc + 2] = v.z; tile[r][lc + 3] = v.w;
        }
        __syncthreads();
        for (int r = lr; r < 64; r += 16) {
            ushort4 o;
            o.x = f2bf(tile[lc + 0][r]); o.y = f2bf(tile[lc + 1][r]);
            o.z = f2bf(tile[lc + 2][r]); o.w = f2bf(tile[lc + 3][r]);
            *(ushort4*)(Wt + (size_t)(n0 + r) * 512 + k0 + lc) = o;
        }
    } else {
        // ---- hist ----
        int e = bid * 256 + t;
        atomicAdd(&cnt[dst[e]], 1);
    }
}

// ---------- bf16 MFMA GEMM (global_load_lds width-16, linear LDS, XCD-swizzled grid) ----------
#define BM 128
#define BN 128
#define BK 64

__global__ __launch_bounds__(256) void k_gemm_bf16(
        const unsigned short* __restrict__ Ab,
        const unsigned short* __restrict__ Bt,
        unsigned short* __restrict__ xl, unsigned short* __restrict__ xr) {
    __shared__ unsigned short As[BM * BK];
    __shared__ unsigned short Bs[BN * BK];
    int t = threadIdx.x;
    int bid = blockIdx.x;
    int xcd = bid & 7, r = bid >> 3;
    int m0 = (xcd * 16 + (r & 15)) * BM;
    int n0 = (r >> 4) * BN;
    int wid = t >> 6, lane = t & 63;
    int wm = (wid >> 1) * 64, wn = (wid & 1) * 64;
    int lrow = lane & 15, quad = lane >> 4;
    floatx4 acc[4][4] = {};
    for (int k0 = 0; k0 < 512; k0 += BK) {
        __syncthreads();
#pragma unroll
        for (int it = 0; it < 4; it++) {
            int cid = it * 256 + t;
            int row = cid >> 3, ch = cid & 7;
            // LDS dest byte = cid*16 = wave_base + lane*16 (linear, matches HW)
            GLD16(Ab + (size_t)(m0 + row) * 512 + k0 + ch * 8, As + cid * 8);
            GLD16(Bt + (size_t)(n0 + row) * 512 + k0 + ch * 8, Bs + cid * 8);
        }
        __syncthreads();
#pragma unroll
        for (int ko = 0; ko < 2; ko++) {
            bf16x8 af[4], bfr[4];
#pragma unroll
            for (int i = 0; i < 4; i++) {
                af[i]  = *(const bf16x8*)&As[(wm + i * 16 + lrow) * BK + ko * 32 + quad * 8];
                bfr[i] = *(const bf16x8*)&Bs[(wn + i * 16 + lrow) * BK + ko * 32 + quad * 8];
            }
#pragma unroll
            for (int i = 0; i < 4; i++)
#pragma unroll
                for (int j = 0; j < 4; j++)
                    acc[i][j] = __builtin_amdgcn_mfma_f32_16x16x32_bf16(af[i], bfr[j], acc[i][j], 0, 0, 0);
        }
    }
#pragma unroll
    for (int i = 0; i < 4; i++) {
        int row = m0 + wm + i * 16 + quad * 4;
#pragma unroll
        for (int j = 0; j < 4; j++) {
            int col = n0 + wn + j * 16 + lrow;
            unsigned short* dstp = (col < 512) ? (xl + (size_t)row * 512 + col)
                                               : (xr + (size_t)row * 512 + (col - 512));
#pragma unroll
            for (int rr = 0; rr < 4; rr++) dstp[(size_t)rr * 512] = f2bf(acc[i][j][rr]);
        }
    }
}

// ---------- fused GATv2 edge phase: 1 wave/block (fine-grain scheduling),
// ---------- 4-wide edge pipeline, SGPR CSR walk, packed math ----------
__global__ __launch_bounds__(64) void k_attn(
        const unsigned short* __restrict__ xl, const unsigned short* __restrict__ xr,
        const int* __restrict__ rp, const int* __restrict__ csrc,
        const float2* __restrict__ ce, const float* __restrict__ We,
        const float* __restrict__ att, const float* __restrict__ bias,
        unsigned short* __restrict__ out) {
    // one node per 64-thread block: CU slot frees per-node, no straggler coupling
    int n = __builtin_amdgcn_readfirstlane(blockIdx.x);
    int lane = threadIdx.x;
    int c0 = lane << 3;
    f32x2 wv0[4], wv1[4], av[4], rv[4];
    {
        float4 a = *(const float4*)(We + c0), b = *(const float4*)(We + c0 + 4);
        wv0[0] = (f32x2){a.x, a.y}; wv0[1] = (f32x2){a.z, a.w};
        wv0[2] = (f32x2){b.x, b.y}; wv0[3] = (f32x2){b.z, b.w};
        a = *(const float4*)(We + 512 + c0); b = *(const float4*)(We + 512 + c0 + 4);
        wv1[0] = (f32x2){a.x, a.y}; wv1[1] = (f32x2){a.z, a.w};
        wv1[2] = (f32x2){b.x, b.y}; wv1[3] = (f32x2){b.z, b.w};
        a = *(const float4*)(att + c0); b = *(const float4*)(att + c0 + 4);
        av[0] = (f32x2){a.x, a.y}; av[1] = (f32x2){a.z, a.w};
        av[2] = (f32x2){b.x, b.y}; av[3] = (f32x2){b.z, b.w};
        uint4 vr = *(const uint4*)(xr + (size_t)n * 512 + c0);
        unpk8v(vr, rv);
    }
    float l = 0.f;
    f32x2 acc[4] = {sp2(0.f), sp2(0.f), sp2(0.f), sp2(0.f)};
    int beg = rp[n], end = rp[n + 1];
    uint4 cv[4];
    float2 cev[4];
    if (beg < end) {
#pragma unroll
        for (int k = 0; k < 4; k++) {
            int q = beg + k; q = (q < end) ? q : end - 1;
            cv[k] = *(const uint4*)(xl + (size_t)csrc[q] * 512 + c0);
            cev[k] = ce[q];
        }
    }
    int i = beg;
    for (; i + 3 < end; i += 4) {
        uint4 a[4]; float2 d[4];
#pragma unroll
        for (int k = 0; k < 4; k++) { a[k] = cv[k]; d[k] = cev[k]; }
#pragma unroll
        for (int k = 0; k < 4; k++) {
            int q = i + 4 + k; q = (q < end) ? q : end - 1;
            cv[k] = *(const uint4*)(xl + (size_t)csrc[q] * 512 + c0);
            cev[k] = ce[q];
        }
        f32x2 lv[4][4];
#pragma unroll
        for (int k = 0; k < 4; k++) unpk8v(a[k], lv[k]);
        float p[4];
#pragma unroll
        for (int k = 0; k < 4; k++) {
            f32x2 dx = sp2(d[k].x), dy = sp2(d[k].y);
            f32x2 pv = sp2(0.f);
#pragma unroll
            for (int j = 0; j < 4; j++) {
                f32x2 v = lv[k][j] + rv[j] + dx * wv0[j] + dy * wv1[j];
                v = pkmax(v, sp2(0.2f) * v);   // leaky_relu(0.2)
                pv += av[j] * v;
            }
            p[k] = pv.x + pv.y;
        }
        // 4 independent 16-lane reduce chains, interleaved
#pragma unroll
        for (int m = 1; m <= 8; m <<= 1) {
#pragma unroll
            for (int k = 0; k < 4; k++) p[k] += __shfl_xor(p[k], m);
        }
        float w[4];
#pragma unroll
        for (int k = 0; k < 4; k++) { w[k] = __expf(fminf(p[k], 60.f)); l += w[k]; }
#pragma unroll
        for (int j = 0; j < 4; j++) {
            f32x2 t0 = sp2(w[0]) * lv[0][j] + sp2(w[1]) * lv[1][j];
            f32x2 t1 = sp2(w[2]) * lv[2][j] + sp2(w[3]) * lv[3][j];
            acc[j] += t0 + t1;
        }
    }
    // tail: cv[k] holds edge min(i+k, end-1) = edge i+k for k < rem
    int rem = end - i;
#pragma unroll
    for (int k = 0; k < 3; k++) {
        if (k < rem) {
            f32x2 lv[4];
            unpk8v(cv[k], lv);
            f32x2 dx = sp2(cev[k].x), dy = sp2(cev[k].y);
            f32x2 pv = sp2(0.f);
#pragma unroll
            for (int j = 0; j < 4; j++) {
                f32x2 v = lv[j] + rv[j] + dx * wv0[j] + dy * wv1[j];
                v = pkmax(v, sp2(0.2f) * v);
                pv += av[j] * v;
            }
            float p = pv.x + pv.y;
            p += __shfl_xor(p, 1);
            p += __shfl_xor(p, 2);
            p += __shfl_xor(p, 4);
            p += __shfl_xor(p, 8);
            float w = __expf(fminf(p, 60.f));
            l += w;
            f32x2 wv = sp2(w);
#pragma unroll
            for (int j = 0; j < 4; j++) acc[j] += wv * lv[j];
        }
    }
    float inv = 1.f / (l + 1e-16f);
    const float* bb = bias + c0;
    float4 b0 = *(const float4*)bb, b1 = *(const float4*)(bb + 4);
    ushort4 o0, o1;
    o0.x = f2bf(acc[0].x * inv + b0.x); o0.y = f2bf(acc[0].y * inv + b0.y);
    o0.z = f2bf(acc[1].x * inv + b0.z); o0.w = f2bf(acc[1].y * inv + b0.w);
    o1.x = f2bf(acc[2].x * inv + b1.x); o1.y = f2bf(acc[2].y * inv + b1.y);
    o1.z = f2bf(acc[3].x * inv + b1.z); o1.w = f2bf(acc[3].y * inv + b1.w);
    *(ushort4*)(out + (size_t)n * 512 + c0) = o0;
    *(ushort4*)(out + (size_t)n * 512 + c0 + 4) = o1;
}

// ---------- BN stats: 256 blocks x 64 rows, uint4 loads, LDS 4-wave reduce ----------
__global__ __launch_bounds__(256) void k_bnstat(const unsigned short* __restrict__ xb,
                                                double* __restrict__ sum,
                                                double* __restrict__ sumsq) {
    __shared__ float ls[4][512];
    __shared__ float lq[4][512];
    int t = threadIdx.x;
    int w = t >> 6, lane = t & 63;
    int c0 = lane << 3;
    int r0 = blockIdx.x * 64 + w * 16;
    f32x2 sv[4] = {sp2(0.f), sp2(0.f), sp2(0.f), sp2(0.f)};
    f32x2 qv[4] = {sp2(0.f), sp2(0.f), sp2(0.f), sp2(0.f)};
#pragma unroll 4
    for (int r = r0; r < r0 + 16; r++) {
        uint4 u = *(const uint4*)(xb + (size_t)r * 512 + c0);
        f32x2 v[4];
        unpk8v(u, v);
#pragma unroll
        for (int j = 0; j < 4; j++) { sv[j] += v[j]; qv[j] += v[j] * v[j]; }
    }
#pragma unroll
    for (int j = 0; j < 4; j++) {
        ls[w][c0 + 2 * j] = sv[j].x; ls[w][c0 + 2 * j + 1] = sv[j].y;
        lq[w][c0 + 2 * j] = qv[j].x; lq[w][c0 + 2 * j + 1] = qv[j].y;
    }
    __syncthreads();
    int c2 = t << 1;
#pragma unroll
    for (int k = 0; k < 2; k++) {
        int c = c2 + k;
        float s4 = ls[0][c] + ls[1][c] + ls[2][c] + ls[3][c];
        float q4 = lq[0][c] + lq[1][c] + lq[2][c] + lq[3][c];
        atomicAdd(sum + c, (double)s4);
        atomicAdd(sumsq + c, (double)q4);
    }
}

// ---------- BN finalize+apply + ELU + optional residual (all bf16 I/O) ----------
__global__ void k_bnapply(const unsigned short* __restrict__ v,
                          const unsigned short* __restrict__ resid,
                          const double* __restrict__ sum, const double* __restrict__ sumsq,
                          const float* __restrict__ g, const float* __restrict__ beta,
                          unsigned short* __restrict__ outb) {
    int i = (blockIdx.x * 256 + threadIdx.x) << 2;
    int c = i & 511;
    ushort4 vu = *(const ushort4*)(v + i);
    double2 s01 = *(const double2*)(sum + c);
    double2 s23 = *(const double2*)(sum + c + 2);
    double2 q01 = *(const double2*)(sumsq + c);
    double2 q23 = *(const double2*)(sumsq + c + 2);
    float4 gg = *(const float4*)(g + c);
    float4 be = *(const float4*)(beta + c);
    const double invN = 1.0 / NN;
    double mu0 = s01.x * invN, mu1 = s01.y * invN, mu2 = s23.x * invN, mu3 = s23.y * invN;
    float sc0 = gg.x * rsqrtf((float)(q01.x * invN - mu0 * mu0) + 1e-5f);
    float sc1 = gg.y * rsqrtf((float)(q01.y * invN - mu1 * mu1) + 1e-5f);
    float sc2 = gg.z * rsqrtf((float)(q23.x * invN - mu2 * mu2) + 1e-5f);
    float sc3 = gg.w * rsqrtf((float)(q23.y * invN - mu3 * mu3) + 1e-5f);
    float y0 = (bf2f(vu.x) - (float)mu0) * sc0 + be.x;
    float y1 = (bf2f(vu.y) - (float)mu1) * sc1 + be.y;
    float y2 = (bf2f(vu.z) - (float)mu2) * sc2 + be.z;
    float y3 = (bf2f(vu.w) - (float)mu3) * sc3 + be.w;
    y0 = y0 > 0.f ? y0 : expm1f(y0);
    y1 = y1 > 0.f ? y1 : expm1f(y1);
    y2 = y2 > 0.f ? y2 : expm1f(y2);
    y3 = y3 > 0.f ? y3 : expm1f(y3);
    if (resid) {
        ushort4 ru = *(const ushort4*)(resid + i);
        y0 += bf2f(ru.x); y1 += bf2f(ru.y); y2 += bf2f(ru.z); y3 += bf2f(ru.w);
    }
    ushort4 o;
    o.x = f2bf(y0); o.y = f2bf(y1); o.z = f2bf(y2); o.w = f2bf(y3);
    *(ushort4*)(outb + i) = o;
}

// ---------- pooling (bf16 in, dword loads: thread t covers channels 2t,2t+1) ----------
__global__ __launch_bounds__(256) void k_pool(const unsigned short* __restrict__ xb,
                                              const int* __restrict__ batch,
                                              float* __restrict__ pooled) {
    __shared__ float lacc[NG][512];
    int t = threadIdx.x;
    for (int i = t; i < NG * 512; i += 256) ((float*)lacc)[i] = 0.f;
    __syncthreads();
    int r0 = blockIdx.x * 64;
    int c2 = t << 1;
    for (int r = r0; r < r0 + 64; r++) {
        int g = batch[r];
        unsigned u = *(const unsigned*)(xb + (size_t)r * 512 + c2);
        lacc[g][c2]     += __uint_as_float(u << 16);
        lacc[g][c2 + 1] += __uint_as_float(u & 0xFFFF0000u);
    }
    __syncthreads();
    int gmin = batch[r0], gmax = batch[r0 + 63];
    for (int g = gmin; g <= gmax; g++)
        for (int i = t; i < 512; i += 256)
            atomicAdd(&pooled[g * 512 + i], lacc[g][i]);
}

// ---------- MLP head, stage 1: h1 partial dots (8 g x 16 c-slices of 32) ----------
__global__ __launch_bounds__(256) void k_head_h1(const float* __restrict__ pooled,
                                                 const float* __restrict__ W1,
                                                 float* __restrict__ h1acc) {
    int g = blockIdx.x >> 4, s = blockIdx.x & 15;
    int o = threadIdx.x;
    int c0 = s * 32;
    float acc = 0.f;
#pragma unroll
    for (int c = 0; c < 32; c++)
        acc += pooled[g * 512 + c0 + c] * W1[(size_t)(c0 + c) * 256 + o];
    atomicAdd(&h1acc[g * 256 + o], acc);
}

// ---------- MLP head, stage 2: finalize h1 (relu(dot/cnt+b1)) slice, emb partials ----------
__global__ __launch_bounds__(256) void k_head_emb(const float* __restrict__ h1acc,
                                                  const int* __restrict__ gcnt,
                                                  const float* __restrict__ b1,
                                                  const float* __restrict__ W2,
                                                  float* __restrict__ embacc) {
    __shared__ float hs[32];
    int g = blockIdx.x >> 3, s = blockIdx.x & 7;
    int c0 = s * 32;
    int t = threadIdx.x;
    if (t < 32) {
        float inv = 1.f / (float)gcnt[g];
        hs[t] = fmaxf(h1acc[g * 256 + c0 + t] * inv + b1[c0 + t], 0.f);
    }
    __syncthreads();
    float acc = 0.f;
#pragma unroll
    for (int c = 0; c < 32; c++)
        acc += hs[c] * W2[(size_t)(c0 + c) * 256 + t];
    atomicAdd(&embacc[g * 256 + t], acc);
}

// ---------- MLP head, stage 3: emb + b2 -> out, logits from LDS ----------
__global__ __launch_bounds__(256) void k_head_fin(const float* __restrict__ embacc,
                                                  const float* __restrict__ b2,
                                                  const float* __restrict__ clsW,
                                                  const float* __restrict__ clsb,
                                                  float* __restrict__ outp) {
    __shared__ float es[256];
    int g = blockIdx.x, o = threadIdx.x;
    float e = embacc[g * 256 + o] + b2[o];
    outp[NG * 12 + g * 256 + o] = e;  // emb
    es[o] = e;
    __syncthreads();
    if (o < 12) {
        float lg = clsb[o];
        for (int c = 0; c < 256; c++) lg += es[c] * clsW[c * 12 + o];
        outp[g * 12 + o] = lg;  // logits
    }
}

extern "C" void kernel_launch(void* const* d_in, const int* in_sizes, int n_in,
                              void* d_out, int out_size, void* d_ws, size_t ws_size,
                              hipStream_t stream) {
    const float* x     = (const float*)d_in[0];
    const float* ea    = (const float*)d_in[1];
    const int*   ei    = (const int*)d_in[2];
    const int*   batch = (const int*)d_in[3];
    const int* src = ei;
    const int* dst = ei + NE;

    float* base = (float*)d_ws;
    size_t off = 0;
    auto alloc = [&](size_t n) -> float* {   // n = FLOAT count (256-aligned)
        float* p = base + off;
        off += (n + 255) & ~(size_t)255;
        return p;
    };
    unsigned short* xl  = (unsigned short*)alloc((size_t)NN * 256);  // [NN,512] bf16
    unsigned short* xr  = (unsigned short*)alloc((size_t)NN * 256);
    unsigned short* Yb  = (unsigned short*)alloc((size_t)NN * 256);  // attn out bf16
    unsigned short* XbA = (unsigned short*)alloc((size_t)NN * 256);  // layer-out ping
    unsigned short* XbB = (unsigned short*)alloc((size_t)NN * 256);  // layer-out pong
    unsigned short* Wt2 = (unsigned short*)alloc(512 * 1024 / 2);
    unsigned short* Wt3 = (unsigned short*)alloc(512 * 1024 / 2);
    int*      rp    = (int*)alloc(NN + 1);
    int*      offp  = (int*)alloc(NN);
    int*      csrc  = (int*)alloc(NE);
    float2*   ce    = (float2*)alloc((size_t)NE * 2);
    // --- zero-init region: cnt | bsum3 | pooled | h1acc | embacc (one memset) ---
    int*      cnt   = (int*)alloc(NN);           // 16384 floats
    double*   bsum3 = (double*)alloc(3 * 2048);  // 6144 floats
    float*    pooled= alloc(NG * 512);           // 4096 floats
    float*    h1acc = alloc(NG * 256);           // 2048 floats
    float*    embacc= alloc(NG * 256);           // 2048 floats
    // --- end zero-init region (30720 floats total) ---
    int*      gcnt  = (int*)alloc(NG);
    float*    outp  = (float*)d_out;  // [0,96): logits, [96,2144): emb

    hipMemsetAsync(cnt, 0, 30720 * sizeof(float), stream);  // cnt+bsum3+pooled+h1acc+embacc
    // merged preamble: hist (blocks 0..1023) + wt4 (1024..1279) + lin1 (1280..5375)
    k_pre<<<5376, 256, 0, stream>>>(dst, cnt,
                                    (const float*)d_in[11], (const float*)d_in[12],
                                    (const float*)d_in[18], (const float*)d_in[19],
                                    Wt2, Wt3,
                                    x, (const float*)d_in[4], (const float*)d_in[5],
                                    xl, xr);
    k_scan<<<1, 1024, 0, stream>>>(cnt, rp, offp, batch, gcnt);
    k_fill<<<NE / 256, 256, 0, stream>>>(dst, src, ea, offp, csrc, ce);

    unsigned short* X = XbA;   // current layer output
    unsigned short* Xp = XbB;  // previous layer output (residual)
    for (int l = 0; l < 3; l++) {
        const float* We  = (const float*)d_in[4 + l * 7 + 2];
        const float* att = (const float*)d_in[4 + l * 7 + 3];
        const float* cb  = (const float*)d_in[4 + l * 7 + 4];
        const float* bg  = (const float*)d_in[4 + l * 7 + 5];
        const float* bb  = (const float*)d_in[4 + l * 7 + 6];

        if (l > 0) {
            k_gemm_bf16<<<1024, 256, 0, stream>>>(Xp, (l == 1) ? Wt2 : Wt3, xl, xr);
        }
        // one node per 64-thread block: finest scheduling granularity
        k_attn<<<NN, 64, 0, stream>>>(xl, xr, rp, csrc, ce, We, att, cb, Yb);

        double* bsum = bsum3 + l * 1024;
        double* bsq  = bsum + 512;
        k_bnstat<<<256, 256, 0, stream>>>(Yb, bsum, bsq);
        k_bnapply<<<(size_t)NN * 512 / 1024, 256, 0, stream>>>(
            Yb, (l == 0) ? nullptr : Xp, bsum, bsq, bg, bb, X);

        unsigned short* tmp = Xp; Xp = X; X = tmp;  // Xp now holds this layer's output
    }

    k_pool<<<NN / 64, 256, 0, stream>>>(Xp, batch, pooled);

    const float* geW1 = (const float*)d_in[25];
    const float* geb1 = (const float*)d_in[26];
    const float* geW2 = (const float*)d_in[27];
    const float* geb2 = (const float*)d_in[28];
    const float* clsW = (const float*)d_in[29];
    const float* clsb = (const float*)d_in[30];

    k_head_h1<<<NG * 16, 256, 0, stream>>>(pooled, geW1, h1acc);
    k_head_emb<<<NG * 8, 256, 0, stream>>>(h1acc, gcnt, geb1, geW2, embacc);
    k_head_fin<<<NG, 256, 0, stream>>>(embacc, geb2, clsW, clsb, outp);
}